// Round 1
// baseline (207.373 us; speedup 1.0000x reference)
//
#include <hip/hip_runtime.h>

typedef __bf16 bf16;
typedef __attribute__((ext_vector_type(8))) __bf16 bf16x8;
typedef __attribute__((ext_vector_type(4))) __bf16 bf16x4;
typedef __attribute__((ext_vector_type(4))) float f32x4;

#define MFMA16(a, b, c) __builtin_amdgcn_mfma_f32_16x16x32_bf16((a), (b), (c), 0, 0, 0)

// Problem constants
#define S_LEN 4096
#define NHEAD 12
#define EMB   768
#define NEGV  (-1e30f)

// ---------------- kernel 0: f32 -> bf16 convert (optionally scaled) -------------
__global__ __launch_bounds__(256) void cvt_kernel(const float* __restrict__ x,
                                                  bf16* __restrict__ o, int n8, float scale) {
  int i = blockIdx.x * 256 + threadIdx.x;
  if (i >= n8) return;
  const float4* p = (const float4*)(x + (size_t)i * 8);
  float4 a = p[0], b = p[1];
  bf16x8 v;
  v[0] = (bf16)(a.x * scale); v[1] = (bf16)(a.y * scale);
  v[2] = (bf16)(a.z * scale); v[3] = (bf16)(a.w * scale);
  v[4] = (bf16)(b.x * scale); v[5] = (bf16)(b.y * scale);
  v[6] = (bf16)(b.z * scale); v[7] = (bf16)(b.w * scale);
  *(bf16x8*)(o + (size_t)i * 8) = v;
}

// ---------------- kernel 1: fused QKV GEMM  out = X @ W^T + bias ----------------
// X: (8192, 768) bf16.  Wb: concat [Wq*0.125; Wk; Wv], each row-major (out,in) =
// B^T layout for the GEMM.  Writes Q,K as (b,h,s,d) bf16; V transposed (b,h,d,s).
// 128x128 tile, BK=64, 4 waves each 64x64 (4x4 of 16x16x32 MFMA).
// LDS XOR swizzle: content 16B-granule c of row r stored at granule c^(r&7).
__global__ __launch_bounds__(256) void qkv_gemm(const bf16* __restrict__ Xb, const bf16* __restrict__ Wb,
                                                const float* __restrict__ bq, const float* __restrict__ bk,
                                                const float* __restrict__ bv,
                                                bf16* __restrict__ Qo, bf16* __restrict__ Ko,
                                                bf16* __restrict__ Vt) {
  __shared__ union SM {
    struct { bf16 a[128 * 64]; bf16 b[128 * 64]; } st;
    bf16 c[128 * 130];  // epilogue transpose buffer (pad 130 vs bank conflicts)
  } sm;
  const int tid = threadIdx.x;
  const int l = tid & 63, w = tid >> 6;
  const int ln = l & 15, g = l >> 4;
  const int wm = w >> 1, wn = w & 1;
  const int m0 = blockIdx.x * 128;
  const int n0 = blockIdx.y * 128;

  const f32x4 zero4 = {0.f, 0.f, 0.f, 0.f};
  f32x4 acc[4][4];
#pragma unroll
  for (int i = 0; i < 4; ++i)
#pragma unroll
    for (int j = 0; j < 4; ++j) acc[i][j] = zero4;

  for (int kt = 0; kt < 12; ++kt) {
    const int k0 = kt * 64;
#pragma unroll
    for (int p = 0; p < 4; ++p) {           // 1024 granules of 16B per 128x64 tile
      int G = p * 256 + tid;
      int row = G >> 3, slot = G & 7;
      int dsl = slot ^ (row & 7);
      bf16x8 va = *(const bf16x8*)(Xb + (size_t)(m0 + row) * 768 + k0 + slot * 8);
      *(bf16x8*)(&sm.st.a[row * 64 + dsl * 8]) = va;
      bf16x8 vb = *(const bf16x8*)(Wb + (size_t)(n0 + row) * 768 + k0 + slot * 8);
      *(bf16x8*)(&sm.st.b[row * 64 + dsl * 8]) = vb;
    }
    __syncthreads();
#pragma unroll
    for (int kc = 0; kc < 2; ++kc) {
      bf16x8 af[4], bfr[4];
#pragma unroll
      for (int i = 0; i < 4; ++i) {
        int ra = wm * 64 + i * 16 + ln;
        af[i] = *(const bf16x8*)(&sm.st.a[ra * 64 + ((kc * 4 + g) ^ (ra & 7)) * 8]);
        int rb = wn * 64 + i * 16 + ln;
        bfr[i] = *(const bf16x8*)(&sm.st.b[rb * 64 + ((kc * 4 + g) ^ (rb & 7)) * 8]);
      }
#pragma unroll
      for (int mi = 0; mi < 4; ++mi)
#pragma unroll
        for (int ni = 0; ni < 4; ++ni)
          acc[mi][ni] = MFMA16(af[mi], bfr[ni], acc[mi][ni]);
    }
    __syncthreads();
  }

  // ----- epilogue -----
  const int which = n0 / 768;           // 0=Q 1=K 2=V (uniform per block)
  const int h0 = (n0 % 768) >> 6;
  const int b = m0 >> 12;
  const int h = h0 + wn;                // head for this wave's column half
  const float bsc = (which == 0) ? 0.125f : 1.0f;
  const float* bias = (which == 0) ? bq : (which == 1) ? bk : bv;
  float bvv[4];
#pragma unroll
  for (int ni = 0; ni < 4; ++ni) bvv[ni] = bias[h * 64 + ni * 16 + ln] * bsc;

  if (which < 2) {
    bf16* dst = (which == 0) ? Qo : Ko;
    const size_t base = ((size_t)(b * NHEAD + h) * S_LEN + (m0 & 4095)) * 64;
#pragma unroll
    for (int mi = 0; mi < 4; ++mi)
#pragma unroll
      for (int ni = 0; ni < 4; ++ni)
#pragma unroll
        for (int r = 0; r < 4; ++r) {
          int sl = wm * 64 + mi * 16 + g * 4 + r;
          dst[base + (size_t)sl * 64 + ni * 16 + ln] = (bf16)(acc[mi][ni][r] + bvv[ni]);
        }
  } else {
    // V: transpose through LDS, write (b,h,d,s)
#pragma unroll
    for (int mi = 0; mi < 4; ++mi)
#pragma unroll
      for (int ni = 0; ni < 4; ++ni)
#pragma unroll
        for (int r = 0; r < 4; ++r) {
          int sl = wm * 64 + mi * 16 + g * 4 + r;
          sm.c[sl * 130 + wn * 64 + ni * 16 + ln] = (bf16)(acc[mi][ni][r] + bvv[ni]);
        }
    __syncthreads();
#pragma unroll
    for (int it = 0; it < 4; ++it) {
      int d = it * 32 + (tid >> 3);     // 0..127 (two heads worth of dims)
      int scp = tid & 7;                // 16-token chunk
      int hh = h0 + (d >> 6);
      bf16x8 o0, o1;
#pragma unroll
      for (int i2 = 0; i2 < 8; ++i2) o0[i2] = sm.c[(scp * 16 + i2) * 130 + d];
#pragma unroll
      for (int i2 = 0; i2 < 8; ++i2) o1[i2] = sm.c[(scp * 16 + 8 + i2) * 130 + d];
      bf16* dp = Vt + ((size_t)(b * NHEAD + hh) * 64 + (d & 63)) * S_LEN + (m0 & 4095) + scp * 16;
      *(bf16x8*)dp = o0;
      *(bf16x8*)(dp + 8) = o1;
    }
  }
}

// ---------------- kernel 2: banded flash attention ----------------
// Block = (64 queries) x (b,h). 4 waves, 16 queries each.
// Swapped QK^T: mfma(K, Q) -> S^T; each lane owns query (l&15), keys in rows.
// PV: mfma(V^T, P^T) -> O^T; acc cols = query, rows = dim.
__global__ __launch_bounds__(256) void attn_kernel(const bf16* __restrict__ Qb, const bf16* __restrict__ Kb,
                                                   const bf16* __restrict__ Vtb,
                                                   const float* __restrict__ amask,
                                                   const unsigned char* __restrict__ imask,
                                                   float* __restrict__ out) {
  __shared__ bf16 Ks[64 * 64];    // [key][dim], swizzled
  __shared__ bf16 Vs[64 * 64];    // [dim][key], swizzled
  __shared__ bf16 Pt[4][16 * 64]; // per-wave P^T as [q][key], 8B-granule swizzle
  __shared__ float Ams[64];
  const int tid = threadIdx.x;
  const int l = tid & 63, w = tid >> 6;
  const int ln = l & 15, g = l >> 4;
  const int bh = blockIdx.y, b = bh / NHEAD, h = bh % NHEAD;
  const int q0 = blockIdx.x * 64;
  const int qg = q0 + w * 16 + ln;      // this lane's query

  const size_t qoff = ((size_t)bh * S_LEN + qg) * 64;
  const bf16x8 qf0 = *(const bf16x8*)(Qb + qoff + g * 8);
  const bf16x8 qf1 = *(const bf16x8*)(Qb + qoff + 32 + g * 8);

  const f32x4 zero4 = {0.f, 0.f, 0.f, 0.f};
  f32x4 acc[4];
#pragma unroll
  for (int i = 0; i < 4; ++i) acc[i] = zero4;
  float mrun = -1e38f, lrun = 0.f;

  for (int t = 0; t < 9; ++t) {
    const int tj0 = q0 - 256 + t * 64;
    if (tj0 < 0 || tj0 >= S_LEN) continue;   // uniform: tiles fully in/out of range
#pragma unroll
    for (int p = 0; p < 2; ++p) {            // stage K (64x64) and V^T (64x64)
      int G = p * 256 + tid;
      int row = G >> 3, slot = G & 7;
      int dsl = slot ^ (row & 7);
      *(bf16x8*)(&Ks[row * 64 + dsl * 8]) =
          *(const bf16x8*)(Kb + ((size_t)bh * S_LEN + tj0 + row) * 64 + slot * 8);
      *(bf16x8*)(&Vs[row * 64 + dsl * 8]) =
          *(const bf16x8*)(Vtb + ((size_t)bh * 64 + row) * S_LEN + tj0 + slot * 8);
    }
    if (tid < 64) Ams[tid] = amask[b * S_LEN + tj0 + tid];
    __syncthreads();

    // QK^T (swapped): S^T[key][q]
    f32x4 sc[4];
#pragma unroll
    for (int i = 0; i < 4; ++i) sc[i] = zero4;
#pragma unroll
    for (int kc = 0; kc < 2; ++kc) {
      bf16x8 qf = kc ? qf1 : qf0;
#pragma unroll
      for (int mi = 0; mi < 4; ++mi) {
        int r = mi * 16 + ln;
        bf16x8 kf = *(const bf16x8*)(&Ks[r * 64 + ((kc * 4 + g) ^ (r & 7)) * 8]);
        sc[mi] = MFMA16(kf, qf, sc[mi]);
      }
    }

    // mask + online softmax (lane owns query qg; its keys: mi*16 + g*4 + r)
    float mt = -1e38f;
    float pv[4][4];
#pragma unroll
    for (int mi = 0; mi < 4; ++mi)
#pragma unroll
      for (int r = 0; r < 4; ++r) {
        int key = mi * 16 + g * 4 + r;
        int j = tj0 + key;
        float v = sc[mi][r];
        bool valid = (j >= qg - 256) && (j <= qg + 256);
        v = valid ? ((Ams[key] != 0.f) ? NEGV : v) : NEGV;
        sc[mi][r] = v;
        mt = fmaxf(mt, v);
      }
    mt = fmaxf(mt, __shfl_xor(mt, 16));
    mt = fmaxf(mt, __shfl_xor(mt, 32));
    float mnew = fmaxf(mrun, mt);
    float corr = __expf(mrun - mnew);
    float psum = 0.f;
#pragma unroll
    for (int mi = 0; mi < 4; ++mi)
#pragma unroll
      for (int r = 0; r < 4; ++r) {
        float p = __expf(sc[mi][r] - mnew);
        pv[mi][r] = p;
        psum += p;
      }
    psum += __shfl_xor(psum, 16);
    psum += __shfl_xor(psum, 32);
    lrun = lrun * corr + psum;
    mrun = mnew;
#pragma unroll
    for (int i = 0; i < 4; ++i) acc[i] *= corr;

    // P^T -> LDS [q][key] with 8B-granule XOR swizzle (granule ^ q)
    bf16* PtW = &Pt[w][0];
#pragma unroll
    for (int mi = 0; mi < 4; ++mi) {
      bf16x4 pk;
      pk[0] = (bf16)pv[mi][0]; pk[1] = (bf16)pv[mi][1];
      pk[2] = (bf16)pv[mi][2]; pk[3] = (bf16)pv[mi][3];
      *(bf16x4*)(&PtW[ln * 64 + ((mi * 4 + g) ^ ln) * 4]) = pk;
    }

    // PV: O^T[d][q] += V^T[d][key] * P^T[key][q]
#pragma unroll
    for (int ds2 = 0; ds2 < 4; ++ds2) {
#pragma unroll
      for (int kc = 0; kc < 2; ++kc) {
        int r = ds2 * 16 + ln;
        bf16x8 vf = *(const bf16x8*)(&Vs[r * 64 + ((kc * 4 + g) ^ (r & 7)) * 8]);
        bf16x4 pa = *(const bf16x4*)(&PtW[ln * 64 + ((kc * 8 + g * 2) ^ ln) * 4]);
        bf16x4 pb = *(const bf16x4*)(&PtW[ln * 64 + ((kc * 8 + g * 2 + 1) ^ ln) * 4]);
        bf16x8 pf = __builtin_shufflevector(pa, pb, 0, 1, 2, 3, 4, 5, 6, 7);
        acc[ds2] = MFMA16(vf, pf, acc[ds2]);
      }
    }
    __syncthreads();
  }

  float rl = 1.0f / lrun;
  if (imask[b * S_LEN + qg] != 0) rl = 0.0f;  // is_index_masked -> zero row
  float* ob = out + ((size_t)b * S_LEN + qg) * EMB + h * 64;
#pragma unroll
  for (int ds2 = 0; ds2 < 4; ++ds2) {
    float4 o;
    o.x = acc[ds2][0] * rl; o.y = acc[ds2][1] * rl;
    o.z = acc[ds2][2] * rl; o.w = acc[ds2][3] * rl;
    *(float4*)(ob + ds2 * 16 + g * 4) = o;
  }
}

extern "C" void kernel_launch(void* const* d_in, const int* in_sizes, int n_in,
                              void* d_out, int out_size, void* d_ws, size_t ws_size,
                              hipStream_t stream) {
  const float* X = (const float*)d_in[0];
  const float* amask = (const float*)d_in[1];
  const unsigned char* imask = (const unsigned char*)d_in[2];
  const float* Wq = (const float*)d_in[3];
  const float* bq = (const float*)d_in[4];
  const float* Wk = (const float*)d_in[5];
  const float* bk = (const float*)d_in[6];
  const float* Wv = (const float*)d_in[7];
  const float* bv = (const float*)d_in[8];
  float* out = (float*)d_out;

  // workspace layout (bf16 elements)
  bf16* Xb = (bf16*)d_ws;                  //  8192*768
  bf16* Wb = Xb + 6291456;                 //  3*768*768 (Wq*0.125, Wk, Wv)
  bf16* Qb = Wb + 3 * 589824;              //  (b,h,s,d)
  bf16* Kb = Qb + 6291456;                 //  (b,h,s,d)
  bf16* Vt = Kb + 6291456;                 //  (b,h,d,s)

  cvt_kernel<<<3072, 256, 0, stream>>>(X, Xb, 6291456 / 8, 1.0f);
  cvt_kernel<<<288, 256, 0, stream>>>(Wq, Wb, 589824 / 8, 0.125f);   // fold 1/sqrt(D)
  cvt_kernel<<<288, 256, 0, stream>>>(Wk, Wb + 589824, 589824 / 8, 1.0f);
  cvt_kernel<<<288, 256, 0, stream>>>(Wv, Wb + 2 * 589824, 589824 / 8, 1.0f);
  qkv_gemm<<<dim3(64, 18), 256, 0, stream>>>(Xb, Wb, bq, bk, bv, Qb, Kb, Vt);
  attn_kernel<<<dim3(64, 24), 256, 0, stream>>>(Qb, Kb, Vt, amask, imask, out);
}

// Round 2
// 186.292 us; speedup vs baseline: 1.1132x; 1.1132x over previous
//
#include <hip/hip_runtime.h>

typedef __bf16 bf16;
typedef __attribute__((ext_vector_type(8))) __bf16 bf16x8;
typedef __attribute__((ext_vector_type(4))) __bf16 bf16x4;
typedef __attribute__((ext_vector_type(4))) float f32x4;

#define MFMA16(a, b, c) __builtin_amdgcn_mfma_f32_16x16x32_bf16((a), (b), (c), 0, 0, 0)

#define S_LEN 4096
#define NHEAD 12
#define EMB   768
#define NEGV  (-1e30f)

// async global->LDS, 16B per lane. LDS dest = wave-uniform base + lane*16 (linear);
// swizzled layouts are achieved by pre-swizzling the per-lane GLOBAL source addr.
__device__ __forceinline__ void gload16(const bf16* g, bf16* l) {
  __builtin_amdgcn_global_load_lds((const __attribute__((address_space(1))) void*)g,
                                   (__attribute__((address_space(3))) void*)l, 16, 0, 0);
}

// ---------------- kernel 0: f32 -> bf16 convert (optionally scaled) -------------
__global__ __launch_bounds__(256) void cvt_kernel(const float* __restrict__ x,
                                                  bf16* __restrict__ o, int n8, float scale) {
  int i = blockIdx.x * 256 + threadIdx.x;
  if (i >= n8) return;
  const float4* p = (const float4*)(x + (size_t)i * 8);
  float4 a = p[0], b = p[1];
  bf16x8 v;
  v[0] = (bf16)(a.x * scale); v[1] = (bf16)(a.y * scale);
  v[2] = (bf16)(a.z * scale); v[3] = (bf16)(a.w * scale);
  v[4] = (bf16)(b.x * scale); v[5] = (bf16)(b.y * scale);
  v[6] = (bf16)(b.z * scale); v[7] = (bf16)(b.w * scale);
  *(bf16x8*)(o + (size_t)i * 8) = v;
}

// three weight matrices in one launch; which = blockIdx.y, Wq gets 1/sqrt(D) folded
__global__ __launch_bounds__(256) void cvt3_kernel(const float* __restrict__ w0,
                                                   const float* __restrict__ w1,
                                                   const float* __restrict__ w2,
                                                   bf16* __restrict__ o, int n8) {
  int which = blockIdx.y;
  const float* src = (which == 0) ? w0 : (which == 1) ? w1 : w2;
  float scale = (which == 0) ? 0.125f : 1.0f;
  int i = blockIdx.x * 256 + threadIdx.x;
  if (i >= n8) return;
  const float4* p = (const float4*)(src + (size_t)i * 8);
  float4 a = p[0], b = p[1];
  bf16x8 v;
  v[0] = (bf16)(a.x * scale); v[1] = (bf16)(a.y * scale);
  v[2] = (bf16)(a.z * scale); v[3] = (bf16)(a.w * scale);
  v[4] = (bf16)(b.x * scale); v[5] = (bf16)(b.y * scale);
  v[6] = (bf16)(b.z * scale); v[7] = (bf16)(b.w * scale);
  *(bf16x8*)(o + ((size_t)which * n8 + i) * 8) = v;
}

// ---------------- kernel 1: fused QKV GEMM  out = X @ W^T + bias ----------------
// 128x128 tile, BK=64, 4 waves. Staging via global_load_lds (linear LDS dest,
// pre-swizzled global source: LDS granule (row,dsl) holds source slot dsl^(row&7)).
__global__ __launch_bounds__(256) void qkv_gemm(const bf16* __restrict__ Xb, const bf16* __restrict__ Wb,
                                                const float* __restrict__ bq, const float* __restrict__ bk,
                                                const float* __restrict__ bv,
                                                bf16* __restrict__ Qo, bf16* __restrict__ Ko,
                                                bf16* __restrict__ Vt) {
  __shared__ union SM {
    struct { bf16 a[128 * 64]; bf16 b[128 * 64]; } st;
    bf16 c[128 * 130];  // epilogue transpose buffer
  } sm;
  const int tid = threadIdx.x;
  const int l = tid & 63, w = tid >> 6;
  const int ln = l & 15, g = l >> 4;
  const int wm = w >> 1, wn = w & 1;
  const int m0 = blockIdx.x * 128;
  const int n0 = blockIdx.y * 128;

  const f32x4 zero4 = {0.f, 0.f, 0.f, 0.f};
  f32x4 acc[4][4];
#pragma unroll
  for (int i = 0; i < 4; ++i)
#pragma unroll
    for (int j = 0; j < 4; ++j) acc[i][j] = zero4;

  for (int kt = 0; kt < 12; ++kt) {
    const int k0 = kt * 64;
#pragma unroll
    for (int i = 0; i < 4; ++i) {
      const int G = w * 256 + i * 64 + l;      // granule id 0..1023
      const int row = G >> 3, dsl = G & 7;
      const int slot = dsl ^ (row & 7);
      gload16(Xb + (size_t)(m0 + row) * 768 + k0 + slot * 8, &sm.st.a[(w * 256 + i * 64) * 8]);
      gload16(Wb + (size_t)(n0 + row) * 768 + k0 + slot * 8, &sm.st.b[(w * 256 + i * 64) * 8]);
    }
    asm volatile("s_waitcnt vmcnt(0)" ::: "memory");
    __syncthreads();
#pragma unroll
    for (int kc = 0; kc < 2; ++kc) {
      bf16x8 af[4], bfr[4];
#pragma unroll
      for (int i = 0; i < 4; ++i) {
        int ra = wm * 64 + i * 16 + ln;
        af[i] = *(const bf16x8*)(&sm.st.a[ra * 64 + ((kc * 4 + g) ^ (ra & 7)) * 8]);
        int rb = wn * 64 + i * 16 + ln;
        bfr[i] = *(const bf16x8*)(&sm.st.b[rb * 64 + ((kc * 4 + g) ^ (rb & 7)) * 8]);
      }
#pragma unroll
      for (int mi = 0; mi < 4; ++mi)
#pragma unroll
        for (int ni = 0; ni < 4; ++ni)
          acc[mi][ni] = MFMA16(af[mi], bfr[ni], acc[mi][ni]);
    }
    __syncthreads();
  }

  // ----- epilogue -----
  const int which = n0 / 768;           // 0=Q 1=K 2=V
  const int h0 = (n0 % 768) >> 6;
  const int b = m0 >> 12;
  const int h = h0 + wn;
  const float bsc = (which == 0) ? 0.125f : 1.0f;
  const float* bias = (which == 0) ? bq : (which == 1) ? bk : bv;
  float bvv[4];
#pragma unroll
  for (int ni = 0; ni < 4; ++ni) bvv[ni] = bias[h * 64 + ni * 16 + ln] * bsc;

  if (which < 2) {
    bf16* dst = (which == 0) ? Qo : Ko;
    const size_t base = ((size_t)(b * NHEAD + h) * S_LEN + (m0 & 4095)) * 64;
#pragma unroll
    for (int mi = 0; mi < 4; ++mi)
#pragma unroll
      for (int ni = 0; ni < 4; ++ni)
#pragma unroll
        for (int r = 0; r < 4; ++r) {
          int sl = wm * 64 + mi * 16 + g * 4 + r;
          dst[base + (size_t)sl * 64 + ni * 16 + ln] = (bf16)(acc[mi][ni][r] + bvv[ni]);
        }
  } else {
    // V: transpose through LDS, write (b,h,d,s)
#pragma unroll
    for (int mi = 0; mi < 4; ++mi)
#pragma unroll
      for (int ni = 0; ni < 4; ++ni)
#pragma unroll
        for (int r = 0; r < 4; ++r) {
          int sl = wm * 64 + mi * 16 + g * 4 + r;
          sm.c[sl * 130 + wn * 64 + ni * 16 + ln] = (bf16)(acc[mi][ni][r] + bvv[ni]);
        }
    __syncthreads();
#pragma unroll
    for (int it = 0; it < 4; ++it) {
      int d = it * 32 + (tid >> 3);
      int scp = tid & 7;
      int hh = h0 + (d >> 6);
      bf16x8 o0, o1;
#pragma unroll
      for (int i2 = 0; i2 < 8; ++i2) o0[i2] = sm.c[(scp * 16 + i2) * 130 + d];
#pragma unroll
      for (int i2 = 0; i2 < 8; ++i2) o1[i2] = sm.c[(scp * 16 + 8 + i2) * 130 + d];
      bf16* dp = Vt + ((size_t)(b * NHEAD + hh) * 64 + (d & 63)) * S_LEN + (m0 & 4095) + scp * 16;
      *(bf16x8*)dp = o0;
      *(bf16x8*)(dp + 8) = o1;
    }
  }
}

// ---------------- kernel 2: banded flash attention ----------------
// Block = 128 queries x (b,h), 8 waves x 16 queries. Double-buffered K/V staging
// via global_load_lds; XCD-bijective block swizzle; swapped QK^T; per-wave P^T LDS.
__global__ __launch_bounds__(512) void attn_kernel(const bf16* __restrict__ Qb, const bf16* __restrict__ Kb,
                                                   const bf16* __restrict__ Vtb,
                                                   const float* __restrict__ amask,
                                                   const unsigned char* __restrict__ imask,
                                                   float* __restrict__ out) {
  __shared__ bf16 Ks[2][64 * 64];    // [key][dim], swizzled content
  __shared__ bf16 Vs[2][64 * 64];    // [dim][key], swizzled content
  __shared__ bf16 Pt[8][16 * 64];    // per-wave P^T [q][key]
  __shared__ float Ams[2][64];       // additive mask (-1e30 or 0)
  const int tid = threadIdx.x;
  const int l = tid & 63, w = tid >> 6;
  const int ln = l & 15, g = l >> 4;
  // XCD swizzle: 768 blocks = 8 * 96, bijective
  const int orig = blockIdx.x;
  const int lb = (orig & 7) * 96 + (orig >> 3);
  const int qc = lb & 31, bh = lb >> 5;
  const int b = bh / NHEAD, h = bh % NHEAD;
  const int q0 = qc * 128;
  const int qg = q0 + w * 16 + ln;

  const size_t qoff = ((size_t)bh * S_LEN + qg) * 64;
  const bf16x8 qf0 = *(const bf16x8*)(Qb + qoff + g * 8);
  const bf16x8 qf1 = *(const bf16x8*)(Qb + qoff + 32 + g * 8);

  const f32x4 zero4 = {0.f, 0.f, 0.f, 0.f};
  f32x4 acc[4];
#pragma unroll
  for (int i = 0; i < 4; ++i) acc[i] = zero4;
  float mrun = -1e38f, lrun = 0.f;

  const int t_lo = (q0 >= 256) ? 0 : ((256 - q0) >> 6);
  int t_hi = (S_LEN + 256 - q0) >> 6;
  if (t_hi > 10) t_hi = 10;

  auto stage = [&](int sb, int t) {
    const int tj0 = q0 - 256 + t * 64;
    const int G = w * 64 + l;                  // granule 0..511 (8 waves x 64)
    const int row = G >> 3, dsl = G & 7;
    const int slot = dsl ^ (row & 7);
    gload16(Kb + ((size_t)bh * S_LEN + tj0 + row) * 64 + slot * 8, &Ks[sb][w * 512]);
    gload16(Vtb + ((size_t)bh * 64 + row) * S_LEN + tj0 + slot * 8, &Vs[sb][w * 512]);
    if (tid < 64) {
      float am = amask[b * S_LEN + tj0 + tid];
      Ams[sb][tid] = (am != 0.f) ? -1e30f : 0.f;
    }
  };

  stage(0, t_lo);
  asm volatile("s_waitcnt vmcnt(0)" ::: "memory");
  __syncthreads();

  int buf = 0;
  for (int t = t_lo; t < t_hi; ++t, buf ^= 1) {
    if (t + 1 < t_hi) stage(buf ^ 1, t + 1);   // prefetch overlaps compute
    const int tj0 = q0 - 256 + t * 64;

    // QK^T (swapped): S^T[key][q]
    f32x4 sc[4];
#pragma unroll
    for (int i = 0; i < 4; ++i) sc[i] = zero4;
    __builtin_amdgcn_s_setprio(1);
#pragma unroll
    for (int kc = 0; kc < 2; ++kc) {
      bf16x8 qf = kc ? qf1 : qf0;
#pragma unroll
      for (int mi = 0; mi < 4; ++mi) {
        int r = mi * 16 + ln;
        bf16x8 kf = *(const bf16x8*)(&Ks[buf][r * 64 + ((kc * 4 + g) ^ (r & 7)) * 8]);
        sc[mi] = MFMA16(kf, qf, sc[mi]);
      }
    }
    __builtin_amdgcn_s_setprio(0);

    // mask + online softmax. Band check only on (uniform per-wave) partial tiles.
    float mt = -1e38f;
    const bool full = (t * 64 >= w * 16 + 15) && (t * 64 <= w * 16 + 449);
    if (full) {
#pragma unroll
      for (int mi = 0; mi < 4; ++mi)
#pragma unroll
        for (int r = 0; r < 4; ++r) {
          int key = mi * 16 + g * 4 + r;
          float v = sc[mi][r] + Ams[buf][key];
          sc[mi][r] = v;
          mt = fmaxf(mt, v);
        }
    } else {
#pragma unroll
      for (int mi = 0; mi < 4; ++mi)
#pragma unroll
        for (int r = 0; r < 4; ++r) {
          int key = mi * 16 + g * 4 + r;
          int j = tj0 + key;
          bool valid = (j >= qg - 256) && (j <= qg + 256);
          float v = valid ? (sc[mi][r] + Ams[buf][key]) : NEGV;
          sc[mi][r] = v;
          mt = fmaxf(mt, v);
        }
    }
    mt = fmaxf(mt, __shfl_xor(mt, 16));
    mt = fmaxf(mt, __shfl_xor(mt, 32));
    // defer-max (T13): only rescale when the tile max moved by > 8
    if (!__all(mt <= mrun + 8.f)) {
      float mnew = fmaxf(mrun, mt);
      float corr = __expf(mrun - mnew);
      lrun *= corr;
#pragma unroll
      for (int i = 0; i < 4; ++i) acc[i] *= corr;
      mrun = mnew;
    }
    float psum = 0.f;
    float pv[4][4];
#pragma unroll
    for (int mi = 0; mi < 4; ++mi)
#pragma unroll
      for (int r = 0; r < 4; ++r) {
        float p = __expf(sc[mi][r] - mrun);
        pv[mi][r] = p;
        psum += p;
      }
    psum += __shfl_xor(psum, 16);
    psum += __shfl_xor(psum, 32);
    lrun += psum;

    // P^T -> per-wave LDS [q][key], 8B-granule XOR swizzle
    bf16* PtW = &Pt[w][0];
#pragma unroll
    for (int mi = 0; mi < 4; ++mi) {
      bf16x4 pk;
      pk[0] = (bf16)pv[mi][0]; pk[1] = (bf16)pv[mi][1];
      pk[2] = (bf16)pv[mi][2]; pk[3] = (bf16)pv[mi][3];
      *(bf16x4*)(&PtW[ln * 64 + ((mi * 4 + g) ^ ln) * 4]) = pk;
    }

    // PV: O^T[d][q] += V^T[d][key] * P^T[key][q]
    __builtin_amdgcn_s_setprio(1);
#pragma unroll
    for (int ds2 = 0; ds2 < 4; ++ds2) {
#pragma unroll
      for (int kc = 0; kc < 2; ++kc) {
        int r = ds2 * 16 + ln;
        bf16x8 vf = *(const bf16x8*)(&Vs[buf][r * 64 + ((kc * 4 + g) ^ (r & 7)) * 8]);
        bf16x4 pa = *(const bf16x4*)(&PtW[ln * 64 + ((kc * 8 + g * 2) ^ ln) * 4]);
        bf16x4 pb = *(const bf16x4*)(&PtW[ln * 64 + ((kc * 8 + g * 2 + 1) ^ ln) * 4]);
        bf16x8 pf = __builtin_shufflevector(pa, pb, 0, 1, 2, 3, 4, 5, 6, 7);
        acc[ds2] = MFMA16(vf, pf, acc[ds2]);
      }
    }
    __builtin_amdgcn_s_setprio(0);

    asm volatile("s_waitcnt vmcnt(0)" ::: "memory");  // drain prefetch before swap
    __syncthreads();
  }

  float rl = 1.0f / lrun;
  if (imask[b * S_LEN + qg] != 0) rl = 0.0f;
  float* ob = out + ((size_t)b * S_LEN + qg) * EMB + h * 64;
#pragma unroll
  for (int ds2 = 0; ds2 < 4; ++ds2) {
    float4 o;
    o.x = acc[ds2][0] * rl; o.y = acc[ds2][1] * rl;
    o.z = acc[ds2][2] * rl; o.w = acc[ds2][3] * rl;
    *(float4*)(ob + ds2 * 16 + g * 4) = o;
  }
}

extern "C" void kernel_launch(void* const* d_in, const int* in_sizes, int n_in,
                              void* d_out, int out_size, void* d_ws, size_t ws_size,
                              hipStream_t stream) {
  const float* X = (const float*)d_in[0];
  const float* amask = (const float*)d_in[1];
  const unsigned char* imask = (const unsigned char*)d_in[2];
  const float* Wq = (const float*)d_in[3];
  const float* bq = (const float*)d_in[4];
  const float* Wk = (const float*)d_in[5];
  const float* bk = (const float*)d_in[6];
  const float* Wv = (const float*)d_in[7];
  const float* bv = (const float*)d_in[8];
  float* out = (float*)d_out;

  bf16* Xb = (bf16*)d_ws;                  //  8192*768
  bf16* Wb = Xb + 6291456;                 //  3*768*768 (Wq*0.125, Wk, Wv)
  bf16* Qb = Wb + 3 * 589824;              //  (b,h,s,d)
  bf16* Kb = Qb + 6291456;                 //  (b,h,s,d)
  bf16* Vt = Kb + 6291456;                 //  (b,h,d,s)

  cvt_kernel<<<3072, 256, 0, stream>>>(X, Xb, 6291456 / 8, 1.0f);
  cvt3_kernel<<<dim3(288, 3), 256, 0, stream>>>(Wq, Wk, Wv, Wb, 589824 / 8);
  qkv_gemm<<<dim3(64, 18), 256, 0, stream>>>(Xb, Wb, bq, bk, bv, Qb, Kb, Vt);
  attn_kernel<<<768, 512, 0, stream>>>(Qb, Kb, Vt, amask, imask, out);
}

// Round 4
// 172.234 us; speedup vs baseline: 1.2040x; 1.0816x over previous
//
#include <hip/hip_runtime.h>

typedef __bf16 bf16;
typedef __attribute__((ext_vector_type(8))) __bf16 bf16x8;
typedef __attribute__((ext_vector_type(4))) __bf16 bf16x4;
typedef __attribute__((ext_vector_type(4))) float f32x4;

#define MFMA16(a, b, c) __builtin_amdgcn_mfma_f32_16x16x32_bf16((a), (b), (c), 0, 0, 0)

#define S_LEN 4096
#define NHEAD 12
#define EMB   768
#define NEGV  (-1e30f)

// async global->LDS, 16B per lane. LDS dest = wave-uniform base + lane*16 (linear);
// swizzled layouts are achieved by pre-swizzling the per-lane GLOBAL source addr.
__device__ __forceinline__ void gload16(const bf16* g, bf16* l) {
  __builtin_amdgcn_global_load_lds((const __attribute__((address_space(1))) void*)g,
                                   (__attribute__((address_space(3))) void*)l, 16, 0, 0);
}

// ---------------- kernel 0: f32 -> bf16 convert (optionally scaled) -------------
__global__ __launch_bounds__(256) void cvt_kernel(const float* __restrict__ x,
                                                  bf16* __restrict__ o, int n8, float scale) {
  int i = blockIdx.x * 256 + threadIdx.x;
  if (i >= n8) return;
  const float4* p = (const float4*)(x + (size_t)i * 8);
  float4 a = p[0], b = p[1];
  bf16x8 v;
  v[0] = (bf16)(a.x * scale); v[1] = (bf16)(a.y * scale);
  v[2] = (bf16)(a.z * scale); v[3] = (bf16)(a.w * scale);
  v[4] = (bf16)(b.x * scale); v[5] = (bf16)(b.y * scale);
  v[6] = (bf16)(b.z * scale); v[7] = (bf16)(b.w * scale);
  *(bf16x8*)(o + (size_t)i * 8) = v;
}

// three weight matrices in one launch; which = blockIdx.y, Wq gets 1/sqrt(D) folded
__global__ __launch_bounds__(256) void cvt3_kernel(const float* __restrict__ w0,
                                                   const float* __restrict__ w1,
                                                   const float* __restrict__ w2,
                                                   bf16* __restrict__ o, int n8) {
  int which = blockIdx.y;
  const float* src = (which == 0) ? w0 : (which == 1) ? w1 : w2;
  float scale = (which == 0) ? 0.125f : 1.0f;
  int i = blockIdx.x * 256 + threadIdx.x;
  if (i >= n8) return;
  const float4* p = (const float4*)(src + (size_t)i * 8);
  float4 a = p[0], b = p[1];
  bf16x8 v;
  v[0] = (bf16)(a.x * scale); v[1] = (bf16)(a.y * scale);
  v[2] = (bf16)(a.z * scale); v[3] = (bf16)(a.w * scale);
  v[4] = (bf16)(b.x * scale); v[5] = (bf16)(b.y * scale);
  v[6] = (bf16)(b.z * scale); v[7] = (bf16)(b.w * scale);
  *(bf16x8*)(o + ((size_t)which * n8 + i) * 8) = v;
}

// ---------------- kernel 1: fused QKV GEMM  out = X @ W^T + bias ----------------
// 128x128 tile, BK=64, 4 waves. Double-buffered global_load_lds staging (T3-min
// 2-phase): stage(t+1) issued BEFORE compute(t); ONE __syncthreads (vmcnt0 drain +
// barrier) per K-step, after the MFMAs — loads fly during compute.
// Epilogue: acc -> LDS -> vectorized 16B stores (Q/K rows; V transposed).
__global__ __launch_bounds__(256) void qkv_gemm(const bf16* __restrict__ Xb, const bf16* __restrict__ Wb,
                                                const float* __restrict__ bq, const float* __restrict__ bk,
                                                const float* __restrict__ bv,
                                                bf16* __restrict__ Qo, bf16* __restrict__ Ko,
                                                bf16* __restrict__ Vt) {
  __shared__ union SM {
    struct { bf16 a[2][128 * 64]; bf16 b2[2][128 * 64]; } st;  // 64KB double-buffered staging
    bf16 c[128 * 130];                                          // epilogue buffer (overlaps)
  } sm;
  const int tid = threadIdx.x;
  const int l = tid & 63, w = tid >> 6;
  const int ln = l & 15, g = l >> 4;
  const int wm = w >> 1, wn = w & 1;
  const int m0 = blockIdx.x * 128;
  const int n0 = blockIdx.y * 128;

  const f32x4 zero4 = {0.f, 0.f, 0.f, 0.f};
  f32x4 acc[4][4];
#pragma unroll
  for (int i = 0; i < 4; ++i)
#pragma unroll
    for (int j = 0; j < 4; ++j) acc[i][j] = zero4;

  // per-thread staging geometry (pre-swizzled global source, linear LDS dest)
  int srow[4], sslot[4];
#pragma unroll
  for (int i = 0; i < 4; ++i) {
    const int G = w * 256 + i * 64 + l;      // granule id 0..1023
    srow[i] = G >> 3;
    sslot[i] = (G & 7) ^ (srow[i] & 7);
  }

  auto stage = [&](int sb, int kt) {
    const int k0 = kt * 64;
#pragma unroll
    for (int i = 0; i < 4; ++i) {
      gload16(Xb + (size_t)(m0 + srow[i]) * 768 + k0 + sslot[i] * 8, &sm.st.a[sb][(w * 256 + i * 64) * 8]);
      gload16(Wb + (size_t)(n0 + srow[i]) * 768 + k0 + sslot[i] * 8, &sm.st.b2[sb][(w * 256 + i * 64) * 8]);
    }
  };

  stage(0, 0);
  __syncthreads();               // drain vmcnt(0) + barrier: buf0 ready

  int buf = 0;
  for (int kt = 0; kt < 12; ++kt, buf ^= 1) {
    if (kt < 11) stage(buf ^ 1, kt + 1);   // in flight across the whole compute phase
#pragma unroll
    for (int kc = 0; kc < 2; ++kc) {
      bf16x8 af[4], bfr[4];
#pragma unroll
      for (int i = 0; i < 4; ++i) {
        int ra = wm * 64 + i * 16 + ln;
        af[i] = *(const bf16x8*)(&sm.st.a[buf][ra * 64 + ((kc * 4 + g) ^ (ra & 7)) * 8]);
        int rb = wn * 64 + i * 16 + ln;
        bfr[i] = *(const bf16x8*)(&sm.st.b2[buf][rb * 64 + ((kc * 4 + g) ^ (rb & 7)) * 8]);
      }
#pragma unroll
      for (int mi = 0; mi < 4; ++mi)
#pragma unroll
        for (int ni = 0; ni < 4; ++ni)
          acc[mi][ni] = MFMA16(af[mi], bfr[ni], acc[mi][ni]);
    }
    __syncthreads();             // single per-step drain (vmcnt0 + lgkm0 + barrier)
  }

  // ----- epilogue: all outputs through LDS, vectorized stores -----
  const int which = n0 / 768;           // 0=Q 1=K 2=V
  const int h0 = (n0 % 768) >> 6;
  const int b = m0 >> 12;
  const int h = h0 + wn;
  const float bsc = (which == 0) ? 0.125f : 1.0f;
  const float* bias = (which == 0) ? bq : (which == 1) ? bk : bv;
  float bvv[4];
#pragma unroll
  for (int ni = 0; ni < 4; ++ni) bvv[ni] = bias[h * 64 + ni * 16 + ln] * bsc;

#pragma unroll
  for (int mi = 0; mi < 4; ++mi)
#pragma unroll
    for (int ni = 0; ni < 4; ++ni)
#pragma unroll
      for (int r = 0; r < 4; ++r) {
        int sl = wm * 64 + mi * 16 + g * 4 + r;
        sm.c[sl * 130 + wn * 64 + ni * 16 + ln] = (bf16)(acc[mi][ni][r] + bvv[ni]);
      }
  __syncthreads();

  if (which < 2) {
    // rows are s, cols are d (2 heads x 64): vectorized 16B copies
    bf16* dst = (which == 0) ? Qo : Ko;
#pragma unroll
    for (int it = 0; it < 8; ++it) {
      int gid = it * 256 + tid;
      int sl = gid >> 4, cg = gid & 15;          // 16 granules of 8 cols per row
      int hh = h0 + (cg >> 3);
      bf16x8 v8 = *(const bf16x8*)(&sm.c[sl * 130 + cg * 8]);
      *(bf16x8*)(dst + ((size_t)(b * NHEAD + hh) * S_LEN + (m0 & 4095) + sl) * 64 + (cg & 7) * 8) = v8;
    }
  } else {
    // V: transposed write (b,h,d,s)
#pragma unroll
    for (int it = 0; it < 4; ++it) {
      int d = it * 32 + (tid >> 3);
      int scp = tid & 7;
      int hh = h0 + (d >> 6);
      bf16x8 o0, o1;
#pragma unroll
      for (int i2 = 0; i2 < 8; ++i2) o0[i2] = sm.c[(scp * 16 + i2) * 130 + d];
#pragma unroll
      for (int i2 = 0; i2 < 8; ++i2) o1[i2] = sm.c[(scp * 16 + 8 + i2) * 130 + d];
      bf16* dp = Vt + ((size_t)(b * NHEAD + hh) * 64 + (d & 63)) * S_LEN + (m0 & 4095) + scp * 16;
      *(bf16x8*)dp = o0;
      *(bf16x8*)(dp + 8) = o1;
    }
  }
}

// ---------------- kernel 2: banded flash attention ----------------
// Block = 128 queries x (b,h), 8 waves x 16 queries. Double-buffered K/V staging
// via global_load_lds; XCD-bijective block swizzle; swapped QK^T; per-wave P^T LDS.
__global__ __launch_bounds__(512) void attn_kernel(const bf16* __restrict__ Qb, const bf16* __restrict__ Kb,
                                                   const bf16* __restrict__ Vtb,
                                                   const float* __restrict__ amask,
                                                   const unsigned char* __restrict__ imask,
                                                   float* __restrict__ out) {
  __shared__ bf16 Ks[2][64 * 64];    // [key][dim], swizzled content
  __shared__ bf16 Vs[2][64 * 64];    // [dim][key], swizzled content
  __shared__ bf16 Pt[8][16 * 64];    // per-wave P^T [q][key]
  __shared__ float Ams[2][64];       // additive mask (-1e30 or 0)
  const int tid = threadIdx.x;
  const int l = tid & 63, w = tid >> 6;
  const int ln = l & 15, g = l >> 4;
  // XCD swizzle: 768 blocks = 8 * 96, bijective
  const int orig = blockIdx.x;
  const int lb = (orig & 7) * 96 + (orig >> 3);
  const int qc = lb & 31, bh = lb >> 5;
  const int b = bh / NHEAD, h = bh % NHEAD;
  const int q0 = qc * 128;
  const int qg = q0 + w * 16 + ln;

  const size_t qoff = ((size_t)bh * S_LEN + qg) * 64;
  const bf16x8 qf0 = *(const bf16x8*)(Qb + qoff + g * 8);
  const bf16x8 qf1 = *(const bf16x8*)(Qb + qoff + 32 + g * 8);

  const f32x4 zero4 = {0.f, 0.f, 0.f, 0.f};
  f32x4 acc[4];
#pragma unroll
  for (int i = 0; i < 4; ++i) acc[i] = zero4;
  float mrun = -1e38f, lrun = 0.f;

  const int t_lo = (q0 >= 256) ? 0 : ((256 - q0) >> 6);
  int t_hi = (S_LEN + 256 - q0) >> 6;
  if (t_hi > 10) t_hi = 10;

  auto stage = [&](int sb, int t) {
    const int tj0 = q0 - 256 + t * 64;
    const int G = w * 64 + l;                  // granule 0..511 (8 waves x 64)
    const int row = G >> 3, dsl = G & 7;
    const int slot = dsl ^ (row & 7);
    gload16(Kb + ((size_t)bh * S_LEN + tj0 + row) * 64 + slot * 8, &Ks[sb][w * 512]);
    gload16(Vtb + ((size_t)bh * 64 + row) * S_LEN + tj0 + slot * 8, &Vs[sb][w * 512]);
    if (tid < 64) {
      float am = amask[b * S_LEN + tj0 + tid];
      Ams[sb][tid] = (am != 0.f) ? -1e30f : 0.f;
    }
  };

  stage(0, t_lo);
  asm volatile("s_waitcnt vmcnt(0)" ::: "memory");
  __syncthreads();

  int buf = 0;
  for (int t = t_lo; t < t_hi; ++t, buf ^= 1) {
    if (t + 1 < t_hi) stage(buf ^ 1, t + 1);   // prefetch overlaps compute
    const int tj0 = q0 - 256 + t * 64;

    // QK^T (swapped): S^T[key][q]
    f32x4 sc[4];
#pragma unroll
    for (int i = 0; i < 4; ++i) sc[i] = zero4;
    __builtin_amdgcn_s_setprio(1);
#pragma unroll
    for (int kc = 0; kc < 2; ++kc) {
      bf16x8 qf = kc ? qf1 : qf0;
#pragma unroll
      for (int mi = 0; mi < 4; ++mi) {
        int r = mi * 16 + ln;
        bf16x8 kf = *(const bf16x8*)(&Ks[buf][r * 64 + ((kc * 4 + g) ^ (r & 7)) * 8]);
        sc[mi] = MFMA16(kf, qf, sc[mi]);
      }
    }
    __builtin_amdgcn_s_setprio(0);

    // mask + online softmax. Band check only on (uniform per-wave) partial tiles.
    float mt = -1e38f;
    const bool full = (t * 64 >= w * 16 + 15) && (t * 64 <= w * 16 + 449);
    if (full) {
#pragma unroll
      for (int mi = 0; mi < 4; ++mi)
#pragma unroll
        for (int r = 0; r < 4; ++r) {
          int key = mi * 16 + g * 4 + r;
          float v = sc[mi][r] + Ams[buf][key];
          sc[mi][r] = v;
          mt = fmaxf(mt, v);
        }
    } else {
#pragma unroll
      for (int mi = 0; mi < 4; ++mi)
#pragma unroll
        for (int r = 0; r < 4; ++r) {
          int key = mi * 16 + g * 4 + r;
          int j = tj0 + key;
          bool valid = (j >= qg - 256) && (j <= qg + 256);
          float v = valid ? (sc[mi][r] + Ams[buf][key]) : NEGV;
          sc[mi][r] = v;
          mt = fmaxf(mt, v);
        }
    }
    mt = fmaxf(mt, __shfl_xor(mt, 16));
    mt = fmaxf(mt, __shfl_xor(mt, 32));
    // defer-max (T13): only rescale when the tile max moved by > 8
    if (!__all(mt <= mrun + 8.f)) {
      float mnew = fmaxf(mrun, mt);
      float corr = __expf(mrun - mnew);
      lrun *= corr;
#pragma unroll
      for (int i = 0; i < 4; ++i) acc[i] *= corr;
      mrun = mnew;
    }
    float psum = 0.f;
    float pv[4][4];
#pragma unroll
    for (int mi = 0; mi < 4; ++mi)
#pragma unroll
      for (int r = 0; r < 4; ++r) {
        float p = __expf(sc[mi][r] - mrun);
        pv[mi][r] = p;
        psum += p;
      }
    psum += __shfl_xor(psum, 16);
    psum += __shfl_xor(psum, 32);
    lrun += psum;

    // P^T -> per-wave LDS [q][key], 8B-granule XOR swizzle
    bf16* PtW = &Pt[w][0];
#pragma unroll
    for (int mi = 0; mi < 4; ++mi) {
      bf16x4 pk;
      pk[0] = (bf16)pv[mi][0]; pk[1] = (bf16)pv[mi][1];
      pk[2] = (bf16)pv[mi][2]; pk[3] = (bf16)pv[mi][3];
      *(bf16x4*)(&PtW[ln * 64 + ((mi * 4 + g) ^ ln) * 4]) = pk;
    }

    // PV: O^T[d][q] += V^T[d][key] * P^T[key][q]
    __builtin_amdgcn_s_setprio(1);
#pragma unroll
    for (int ds2 = 0; ds2 < 4; ++ds2) {
#pragma unroll
      for (int kc = 0; kc < 2; ++kc) {
        int r = ds2 * 16 + ln;
        bf16x8 vf = *(const bf16x8*)(&Vs[buf][r * 64 + ((kc * 4 + g) ^ (r & 7)) * 8]);
        bf16x4 pa = *(const bf16x4*)(&PtW[ln * 64 + ((kc * 8 + g * 2) ^ ln) * 4]);
        bf16x4 pb = *(const bf16x4*)(&PtW[ln * 64 + ((kc * 8 + g * 2 + 1) ^ ln) * 4]);
        bf16x8 pf = __builtin_shufflevector(pa, pb, 0, 1, 2, 3, 4, 5, 6, 7);
        acc[ds2] = MFMA16(vf, pf, acc[ds2]);
      }
    }
    __builtin_amdgcn_s_setprio(0);

    asm volatile("s_waitcnt vmcnt(0)" ::: "memory");  // drain prefetch before swap
    __syncthreads();
  }

  float rl = 1.0f / lrun;
  if (imask[b * S_LEN + qg] != 0) rl = 0.0f;
  float* ob = out + ((size_t)b * S_LEN + qg) * EMB + h * 64;
#pragma unroll
  for (int ds2 = 0; ds2 < 4; ++ds2) {
    float4 o;
    o.x = acc[ds2][0] * rl; o.y = acc[ds2][1] * rl;
    o.z = acc[ds2][2] * rl; o.w = acc[ds2][3] * rl;
    *(float4*)(ob + ds2 * 16 + g * 4) = o;
  }
}

extern "C" void kernel_launch(void* const* d_in, const int* in_sizes, int n_in,
                              void* d_out, int out_size, void* d_ws, size_t ws_size,
                              hipStream_t stream) {
  const float* X = (const float*)d_in[0];
  const float* amask = (const float*)d_in[1];
  const unsigned char* imask = (const unsigned char*)d_in[2];
  const float* Wq = (const float*)d_in[3];
  const float* bq = (const float*)d_in[4];
  const float* Wk = (const float*)d_in[5];
  const float* bk = (const float*)d_in[6];
  const float* Wv = (const float*)d_in[7];
  const float* bv = (const float*)d_in[8];
  float* out = (float*)d_out;

  bf16* Xb = (bf16*)d_ws;                  //  8192*768
  bf16* Wb = Xb + 6291456;                 //  3*768*768 (Wq*0.125, Wk, Wv)
  bf16* Qb = Wb + 3 * 589824;              //  (b,h,s,d)
  bf16* Kb = Qb + 6291456;                 //  (b,h,s,d)
  bf16* Vt = Kb + 6291456;                 //  (b,h,d,s)

  cvt_kernel<<<3072, 256, 0, stream>>>(X, Xb, 6291456 / 8, 1.0f);
  cvt3_kernel<<<dim3(288, 3), 256, 0, stream>>>(Wq, Wk, Wv, Wb, 589824 / 8);
  qkv_gemm<<<dim3(64, 18), 256, 0, stream>>>(Xb, Wb, bq, bk, bv, Qb, Kb, Vt);
  attn_kernel<<<768, 512, 0, stream>>>(Qb, Kb, Vt, amask, imask, out);
}